// Round 1
// baseline (362.487 us; speedup 1.0000x reference)
//
#include <hip/hip_runtime.h>
#include <math.h>

// WeightedRankPairwiseLoss2: B=2048, C=32000, scores fp32, targets int32.
// Per row: rank = #(s > gt) + #(s == gt && j < target)  [stable argsort semantics]
//          hinge = sum_{j != t} relu(1 + s_j - gt)
//          weight = rank==0 ? 0 : H(rank)/rank
// out = mean_b(weight * hinge)

#define THREADS 256

__global__ __launch_bounds__(THREADS) void wrpl_row_kernel(
    const float* __restrict__ scores,
    const int* __restrict__ targets,
    float* __restrict__ row_out,
    int C)
{
    const int b = blockIdx.x;
    const float* __restrict__ row = scores + (size_t)b * (size_t)C;
    const int tgt = targets[b];
    const float gt = row[tgt];   // broadcast load, all lanes same address

    const int tid = threadIdx.x;
    const float4* __restrict__ row4 = (const float4*)row;
    const int n4 = C >> 2;       // C divisible by 4 (32000)

    float hsum = 0.0f;
    int cnt = 0;   // strictly greater
    int tie = 0;   // equal with smaller index (stable-sort ordering)

    for (int i = tid; i < n4; i += THREADS) {
        float4 v = row4[i];
        int base = i << 2;
        {
            float s = v.x; float l = 1.0f + s - gt;
            hsum += (l > 0.0f) ? l : 0.0f;
            cnt += (s > gt);
            tie += ((s == gt) && (base + 0 < tgt));
        }
        {
            float s = v.y; float l = 1.0f + s - gt;
            hsum += (l > 0.0f) ? l : 0.0f;
            cnt += (s > gt);
            tie += ((s == gt) && (base + 1 < tgt));
        }
        {
            float s = v.z; float l = 1.0f + s - gt;
            hsum += (l > 0.0f) ? l : 0.0f;
            cnt += (s > gt);
            tie += ((s == gt) && (base + 2 < tgt));
        }
        {
            float s = v.w; float l = 1.0f + s - gt;
            hsum += (l > 0.0f) ? l : 0.0f;
            cnt += (s > gt);
            tie += ((s == gt) && (base + 3 < tgt));
        }
    }

    // wave (64-lane) shuffle reduction
    for (int off = 32; off > 0; off >>= 1) {
        hsum += __shfl_down(hsum, off, 64);
        cnt  += __shfl_down(cnt,  off, 64);
        tie  += __shfl_down(tie,  off, 64);
    }

    __shared__ float sh_h[THREADS / 64];
    __shared__ int   sh_c[THREADS / 64];
    __shared__ int   sh_t[THREADS / 64];
    const int wave = tid >> 6;
    const int lane = tid & 63;
    if (lane == 0) { sh_h[wave] = hsum; sh_c[wave] = cnt; sh_t[wave] = tie; }
    __syncthreads();

    if (tid == 0) {
        float hinge = 0.0f;
        int rank = 0;
        #pragma unroll
        for (int w = 0; w < THREADS / 64; ++w) {
            hinge += sh_h[w];
            rank  += sh_c[w] + sh_t[w];
        }
        // remove the target's own term: relu(1 + gt - gt) = 1
        hinge -= 1.0f;

        double result;
        if (rank == 0) {
            result = 0.0;
        } else {
            double H;
            if (rank <= 128) {
                H = 0.0;
                for (int i = 1; i <= rank; ++i) H += 1.0 / (double)i;
            } else {
                double n = (double)rank;
                // H(n) = ln(n) + gamma + 1/(2n) - 1/(12n^2) + 1/(120n^4) + O(n^-6)
                H = log(n) + 0.577215664901532860606512
                  + 1.0 / (2.0 * n)
                  - 1.0 / (12.0 * n * n)
                  + 1.0 / (120.0 * n * n * n * n);
            }
            result = (H / (double)rank) * (double)hinge;
        }
        row_out[b] = (float)result;
    }
}

__global__ __launch_bounds__(THREADS) void wrpl_reduce_kernel(
    const float* __restrict__ row_vals,
    float* __restrict__ out,
    int B)
{
    const int tid = threadIdx.x;
    double s = 0.0;
    for (int i = tid; i < B; i += THREADS) s += (double)row_vals[i];

    for (int off = 32; off > 0; off >>= 1)
        s += __shfl_down(s, off, 64);

    __shared__ double sh[THREADS / 64];
    const int wave = tid >> 6;
    const int lane = tid & 63;
    if (lane == 0) sh[wave] = s;
    __syncthreads();

    if (tid == 0) {
        double total = 0.0;
        #pragma unroll
        for (int w = 0; w < THREADS / 64; ++w) total += sh[w];
        out[0] = (float)(total / (double)B);
    }
}

extern "C" void kernel_launch(void* const* d_in, const int* in_sizes, int n_in,
                              void* d_out, int out_size, void* d_ws, size_t ws_size,
                              hipStream_t stream) {
    const float* scores  = (const float*)d_in[0];
    const int*   targets = (const int*)d_in[1];
    const int B = in_sizes[1];
    const int C = in_sizes[0] / B;

    float* row_vals = (float*)d_ws;   // B floats of scratch

    wrpl_row_kernel<<<B, THREADS, 0, stream>>>(scores, targets, row_vals, C);
    wrpl_reduce_kernel<<<1, THREADS, 0, stream>>>(row_vals, (float*)d_out, B);
}

// Round 2
// 359.172 us; speedup vs baseline: 1.0092x; 1.0092x over previous
//
#include <hip/hip_runtime.h>
#include <math.h>

// WeightedRankPairwiseLoss2: B=2048, C=32000, scores fp32, targets int32.
// Per row: rank = #(s > gt) + #(s == gt && j < target)  [stable argsort semantics]
//          hinge = sum_{j != t} relu(1 + s_j - gt)
//          weight = rank==0 ? 0 : H(rank)/rank
// out = mean_b(weight * hinge)
//
// Single kernel: one block per row, 4x-unrolled float4 grid-stride loop for
// MLP, wave shuffle + LDS reduce, thread 0 computes H(rank) and atomicAdd's
// the per-row mean contribution into d_out (zeroed by a captured memset).

#define THREADS 256

__device__ __forceinline__ void acc_elem(float s, float gt, int idx, int tgt,
                                         float& h, int& cnt, int& tie) {
    h += fmaxf(s - gt + 1.0f, 0.0f);
    cnt += (s > gt);
    tie += ((s == gt) && (idx < tgt));
}

__global__ __launch_bounds__(THREADS) void wrpl_kernel(
    const float* __restrict__ scores,
    const int* __restrict__ targets,
    float* __restrict__ out,
    int C, float invB)
{
    const int b = blockIdx.x;
    const float* __restrict__ row = scores + (size_t)b * (size_t)C;
    const int tgt = targets[b];
    const float gt = row[tgt];   // broadcast load

    const int tid = threadIdx.x;
    const float4* __restrict__ row4 = (const float4*)row;
    const int n4 = C >> 2;       // C divisible by 4 (32000)

    float h0 = 0.0f, h1 = 0.0f, h2 = 0.0f, h3 = 0.0f;
    int cnt = 0, tie = 0;

    int i = tid;
    // 4x unrolled: 4 independent float4 loads in flight per thread
    for (; i + 3 * THREADS < n4; i += 4 * THREADS) {
        float4 va = row4[i];
        float4 vb = row4[i + THREADS];
        float4 vc = row4[i + 2 * THREADS];
        float4 vd = row4[i + 3 * THREADS];
        int ba = i << 2, bb = (i + THREADS) << 2,
            bc = (i + 2 * THREADS) << 2, bd = (i + 3 * THREADS) << 2;
        acc_elem(va.x, gt, ba + 0, tgt, h0, cnt, tie);
        acc_elem(va.y, gt, ba + 1, tgt, h0, cnt, tie);
        acc_elem(va.z, gt, ba + 2, tgt, h0, cnt, tie);
        acc_elem(va.w, gt, ba + 3, tgt, h0, cnt, tie);
        acc_elem(vb.x, gt, bb + 0, tgt, h1, cnt, tie);
        acc_elem(vb.y, gt, bb + 1, tgt, h1, cnt, tie);
        acc_elem(vb.z, gt, bb + 2, tgt, h1, cnt, tie);
        acc_elem(vb.w, gt, bb + 3, tgt, h1, cnt, tie);
        acc_elem(vc.x, gt, bc + 0, tgt, h2, cnt, tie);
        acc_elem(vc.y, gt, bc + 1, tgt, h2, cnt, tie);
        acc_elem(vc.z, gt, bc + 2, tgt, h2, cnt, tie);
        acc_elem(vc.w, gt, bc + 3, tgt, h2, cnt, tie);
        acc_elem(vd.x, gt, bd + 0, tgt, h3, cnt, tie);
        acc_elem(vd.y, gt, bd + 1, tgt, h3, cnt, tie);
        acc_elem(vd.z, gt, bd + 2, tgt, h3, cnt, tie);
        acc_elem(vd.w, gt, bd + 3, tgt, h3, cnt, tie);
    }
    for (; i < n4; i += THREADS) {
        float4 v = row4[i];
        int base = i << 2;
        acc_elem(v.x, gt, base + 0, tgt, h0, cnt, tie);
        acc_elem(v.y, gt, base + 1, tgt, h0, cnt, tie);
        acc_elem(v.z, gt, base + 2, tgt, h0, cnt, tie);
        acc_elem(v.w, gt, base + 3, tgt, h0, cnt, tie);
    }

    float hsum = (h0 + h1) + (h2 + h3);

    // wave (64-lane) shuffle reduction
    for (int off = 32; off > 0; off >>= 1) {
        hsum += __shfl_down(hsum, off, 64);
        cnt  += __shfl_down(cnt,  off, 64);
        tie  += __shfl_down(tie,  off, 64);
    }

    __shared__ float sh_h[THREADS / 64];
    __shared__ int   sh_c[THREADS / 64];
    __shared__ int   sh_t[THREADS / 64];
    const int wave = tid >> 6;
    const int lane = tid & 63;
    if (lane == 0) { sh_h[wave] = hsum; sh_c[wave] = cnt; sh_t[wave] = tie; }
    __syncthreads();

    if (tid == 0) {
        float hinge = 0.0f;
        int rank = 0;
        #pragma unroll
        for (int w = 0; w < THREADS / 64; ++w) {
            hinge += sh_h[w];
            rank  += sh_c[w] + sh_t[w];
        }
        // remove the target's own term: relu(1 + gt - gt) = 1
        hinge -= 1.0f;

        if (rank > 0) {
            double H;
            if (rank <= 128) {
                H = 0.0;
                for (int k = 1; k <= rank; ++k) H += 1.0 / (double)k;
            } else {
                double n = (double)rank;
                // H(n) = ln(n) + gamma + 1/(2n) - 1/(12n^2) + 1/(120n^4)
                H = log(n) + 0.577215664901532860606512
                  + 1.0 / (2.0 * n)
                  - 1.0 / (12.0 * n * n)
                  + 1.0 / (120.0 * n * n * n * n);
            }
            float contrib = (float)((H / (double)rank) * (double)hinge) * invB;
            atomicAdd(out, contrib);
        }
    }
}

extern "C" void kernel_launch(void* const* d_in, const int* in_sizes, int n_in,
                              void* d_out, int out_size, void* d_ws, size_t ws_size,
                              hipStream_t stream) {
    const float* scores  = (const float*)d_in[0];
    const int*   targets = (const int*)d_in[1];
    const int B = in_sizes[1];
    const int C = in_sizes[0] / B;

    hipMemsetAsync(d_out, 0, sizeof(float) * out_size, stream);
    wrpl_kernel<<<B, THREADS, 0, stream>>>(scores, targets, (float*)d_out,
                                           C, 1.0f / (float)B);
}